// Round 1
// baseline (263.140 us; speedup 1.0000x reference)
//
#include <hip/hip_runtime.h>

namespace {

constexpr int NPAIRS = 40000;
constexpr int F = 128;
constexpr long NF = (long)NPAIRS * F;  // 5,120,000 elements per (l,m) plane

// ---------------------------------------------------------------------------
// Kernel A: s[n,f] = (sum_k w1[f,k] h[n,k]) * (sum_k w2[f,k] h[n,k])
// Written into plane 0 of d_out (an identically-zero output plane, reclaimed
// later by the TP kernel).
// Block: 256 threads, 64 n-rows per block. 40000 = 625 * 64 exactly.
// ---------------------------------------------------------------------------
__global__ __launch_bounds__(256) void s_kernel(const float* __restrict__ g,
                                                const float* __restrict__ w1,
                                                const float* __restrict__ w2,
                                                float* __restrict__ s_out) {
  __shared__ float ht[128][64];    // h transposed: ht[k][n_local]   (32 KB)
  __shared__ float wt1[32][132];   // w1 chunk transposed: [k_local][f] (+pad)
  __shared__ float wt2[32][132];

  const int tid = threadIdx.x;
  const int blk = blockIdx.x;

  // Phase A: Hermite-function recurrence. Wave 0 (tids 0..63) only; one n per lane.
  if (tid < 64) {
    const float gv = g[blk * 64 + tid];
    float hkm1 = 0.75112554446494248286f * expf(-0.5f * gv * gv);  // pi^-1/4 * exp(-g^2/2)
    float hk = 1.41421356237309504880f * gv * hkm1;                // sqrt(2) g h0
    ht[0][tid] = hkm1;
    ht[1][tid] = hk;
#pragma unroll 1
    for (int k = 1; k <= 126; ++k) {
      const float kf = (float)k;
      const float hkp1 =
          sqrtf(2.0f / (kf + 1.0f)) * gv * hk - sqrtf(kf / (kf + 1.0f)) * hkm1;
      ht[k + 1][tid] = hkp1;
      hkm1 = hk;
      hk = hkp1;
    }
  }

  const int fg = tid & 31;  // f-group: f = fg*4 + j
  const int ng = tid >> 5;  // n-group: n_local = ng*8 + i

  float acc1[8][4];
  float acc2[8][4];
#pragma unroll
  for (int i = 0; i < 8; ++i)
#pragma unroll
    for (int j = 0; j < 4; ++j) {
      acc1[i][j] = 0.f;
      acc2[i][j] = 0.f;
    }

  for (int kc = 0; kc < 4; ++kc) {
    // Stage w1/w2 chunk [128 f x 32 k], transposed into LDS [k][f].
#pragma unroll
    for (int it = 0; it < 4; ++it) {
      const int lin = tid + it * 256;  // 0..1023
      const int f = lin >> 3;          // 0..127
      const int kq = lin & 7;          // float4 index along k
      const float4 v1 = *(const float4*)(w1 + f * 128 + kc * 32 + kq * 4);
      const float4 v2 = *(const float4*)(w2 + f * 128 + kc * 32 + kq * 4);
      wt1[kq * 4 + 0][f] = v1.x;
      wt1[kq * 4 + 1][f] = v1.y;
      wt1[kq * 4 + 2][f] = v1.z;
      wt1[kq * 4 + 3][f] = v1.w;
      wt2[kq * 4 + 0][f] = v2.x;
      wt2[kq * 4 + 1][f] = v2.y;
      wt2[kq * 4 + 2][f] = v2.z;
      wt2[kq * 4 + 3][f] = v2.w;
    }
    __syncthreads();  // also covers initial ht writes on the first iteration

#pragma unroll
    for (int kk = 0; kk < 32; ++kk) {
      const float4 wv1 = *(const float4*)&wt1[kk][fg * 4];
      const float4 wv2 = *(const float4*)&wt2[kk][fg * 4];
      const float4 ha = *(const float4*)&ht[kc * 32 + kk][ng * 8];
      const float4 hb = *(const float4*)&ht[kc * 32 + kk][ng * 8 + 4];
      const float hv[8] = {ha.x, ha.y, ha.z, ha.w, hb.x, hb.y, hb.z, hb.w};
#pragma unroll
      for (int i = 0; i < 8; ++i) {
        acc1[i][0] = fmaf(hv[i], wv1.x, acc1[i][0]);
        acc1[i][1] = fmaf(hv[i], wv1.y, acc1[i][1]);
        acc1[i][2] = fmaf(hv[i], wv1.z, acc1[i][2]);
        acc1[i][3] = fmaf(hv[i], wv1.w, acc1[i][3]);
        acc2[i][0] = fmaf(hv[i], wv2.x, acc2[i][0]);
        acc2[i][1] = fmaf(hv[i], wv2.y, acc2[i][1]);
        acc2[i][2] = fmaf(hv[i], wv2.z, acc2[i][2]);
        acc2[i][3] = fmaf(hv[i], wv2.w, acc2[i][3]);
      }
    }
    __syncthreads();  // protect wt reuse next chunk
  }

#pragma unroll
  for (int i = 0; i < 8; ++i) {
    const long n = (long)blk * 64 + ng * 8 + i;
    float4 sv;
    sv.x = acc1[i][0] * acc2[i][0];
    sv.y = acc1[i][1] * acc2[i][1];
    sv.z = acc1[i][2] * acc2[i][2];
    sv.w = acc1[i][3] * acc2[i][3];
    *(float4*)(s_out + n * 128 + fg * 4) = sv;
  }
}

// ---------------------------------------------------------------------------
// Kernel B: out[o,n,f] = s[n,f] * sum_{a,b} (cg[o,a,b]+cg[o,b,a]) x[a,n,f] y[b,n,f]
// s lives in plane 0 of `out`; each thread reads its s before overwriting.
// One float2 (n, f pair) per thread; fully coalesced.
// ---------------------------------------------------------------------------
__global__ __launch_bounds__(256) void tp_kernel(const float* __restrict__ x,
                                                 const float* __restrict__ y,
                                                 const float* __restrict__ cg,
                                                 float* out) {
  __shared__ float d[15 * 15 * 15];
  const int tid = threadIdx.x;
  for (int idx = tid; idx < 3375; idx += 256) {
    const int o = idx / 225;
    const int r = idx - o * 225;
    const int a = r / 15;
    const int b = r - a * 15;
    d[idx] = cg[idx] + cg[(o * 15 + b) * 15 + a];
  }
  __syncthreads();

  const long i = (long)blockIdx.x * 256 + tid;  // 0 .. 2,559,999
  const long off = 2 * i;                       // float2 offset within a plane

  float2 xv[15], yv[15];
#pragma unroll
  for (int a = 0; a < 15; ++a) xv[a] = *(const float2*)(x + a * NF + off);
#pragma unroll
  for (int b = 0; b < 15; ++b) yv[b] = *(const float2*)(y + b * NF + off);
  const float2 sv = *(const float2*)(out + off);  // s from plane 0 (own offset only)

#pragma unroll
  for (int o = 0; o < 15; ++o) {
    const int l3 = o / 5;
    const int m3 = o % 5 - 2;
    float2 acc = make_float2(0.f, 0.f);
    if (m3 >= -l3 && m3 <= l3) {
#pragma unroll
      for (int l1 = 0; l1 < 3; ++l1) {
#pragma unroll
        for (int l2 = 0; l2 < 3; ++l2) {
          const int ldiff = (l1 > l2) ? (l1 - l2) : (l2 - l1);
          if (l3 < ldiff || l3 > l1 + l2) continue;
          const int mlo = (-l1 > m3 - l2) ? -l1 : (m3 - l2);
          const int mhi = (l1 < m3 + l2) ? l1 : (m3 + l2);
#pragma unroll
          for (int m1 = mlo; m1 <= mhi; ++m1) {
            const int m2 = m3 - m1;
            const int a = l1 * 5 + m1 + 2;
            const int b = l2 * 5 + m2 + 2;
            const float dv = d[(o * 15 + a) * 15 + b];
            acc.x = fmaf(dv, xv[a].x * yv[b].x, acc.x);
            acc.y = fmaf(dv, xv[a].y * yv[b].y, acc.y);
          }
        }
      }
    }
    float2 res;
    res.x = acc.x * sv.x;
    res.y = acc.y * sv.y;
    *(float2*)(out + o * NF + off) = res;
  }
}

}  // namespace

extern "C" void kernel_launch(void* const* d_in, const int* in_sizes, int n_in,
                              void* d_out, int out_size, void* d_ws, size_t ws_size,
                              hipStream_t stream) {
  const float* x = (const float*)d_in[0];
  const float* y = (const float*)d_in[1];
  const float* g = (const float*)d_in[2];
  const float* w1 = (const float*)d_in[3];
  const float* w2 = (const float*)d_in[4];
  const float* cg = (const float*)d_in[5];
  float* out = (float*)d_out;

  // Pass 1: s[n,f] -> plane 0 of out (a guaranteed-zero output plane).
  s_kernel<<<625, 256, 0, stream>>>(g, w1, w2, out);
  // Pass 2: streaming tensor-product contraction; overwrites all 15 planes.
  tp_kernel<<<10000, 256, 0, stream>>>(x, y, cg, out);
}

// Round 2
// 228.062 us; speedup vs baseline: 1.1538x; 1.1538x over previous
//
#include <hip/hip_runtime.h>

namespace {

constexpr int NPAIRS = 40000;
constexpr int F = 128;
constexpr long NF = (long)NPAIRS * F;  // 5,120,000 elements per (l,m) plane

// ---------------------------------------------------------------------------
// Kernel A: s[n,f] = (sum_k w1[f,k] h[n,k]) * (sum_k w2[f,k] h[n,k])
// 32 n-rows per block, 1250 blocks, k-chunks of 16 (LDS ~33 KB -> 4 blocks/CU).
// Thread tile 4n x 4f: 32 FMA per 3 ds_read_b128 -> FMA-throughput bound.
// ---------------------------------------------------------------------------
__global__ __launch_bounds__(256, 4) void s_kernel(const float* __restrict__ g,
                                                   const float* __restrict__ w1,
                                                   const float* __restrict__ w2,
                                                   float* __restrict__ s_out) {
  __shared__ float ht[128][32];    // h transposed: ht[k][n_local]  (16 KB)
  __shared__ float wt1[16][132];   // w chunk transposed: [k_local][f] (+pad)
  __shared__ float wt2[16][132];

  const int tid = threadIdx.x;
  const int blk = blockIdx.x;

  // Hermite-function recurrence: lanes 0..31, one n per lane.
  if (tid < 32) {
    const float gv = g[blk * 32 + tid];
    float hkm1 = 0.75112554446494248286f * expf(-0.5f * gv * gv);  // pi^-1/4 e^{-g^2/2}
    float hk = 1.41421356237309504880f * gv * hkm1;
    ht[0][tid] = hkm1;
    ht[1][tid] = hk;
#pragma unroll 1
    for (int k = 1; k <= 126; ++k) {
      const float kf = (float)k;
      const float hkp1 =
          sqrtf(2.0f / (kf + 1.0f)) * gv * hk - sqrtf(kf / (kf + 1.0f)) * hkm1;
      ht[k + 1][tid] = hkp1;
      hkm1 = hk;
      hk = hkp1;
    }
  }

  const int fg = tid & 31;  // f = fg*4 + j
  const int ng = tid >> 5;  // n_local = ng*4 + i

  float acc1[4][4];
  float acc2[4][4];
#pragma unroll
  for (int i = 0; i < 4; ++i)
#pragma unroll
    for (int j = 0; j < 4; ++j) {
      acc1[i][j] = 0.f;
      acc2[i][j] = 0.f;
    }

  for (int kc = 0; kc < 8; ++kc) {
    // Stage w1/w2 chunk [128 f x 16 k], transposed into LDS [k][f].
#pragma unroll
    for (int it = 0; it < 2; ++it) {
      const int lin = tid + it * 256;  // 0..511
      const int f = lin >> 2;          // 0..127
      const int kq = lin & 3;          // float4 index along k (k = kq*4+j)
      const float4 v1 = *(const float4*)(w1 + f * 128 + kc * 16 + kq * 4);
      const float4 v2 = *(const float4*)(w2 + f * 128 + kc * 16 + kq * 4);
      wt1[kq * 4 + 0][f] = v1.x;
      wt1[kq * 4 + 1][f] = v1.y;
      wt1[kq * 4 + 2][f] = v1.z;
      wt1[kq * 4 + 3][f] = v1.w;
      wt2[kq * 4 + 0][f] = v2.x;
      wt2[kq * 4 + 1][f] = v2.y;
      wt2[kq * 4 + 2][f] = v2.z;
      wt2[kq * 4 + 3][f] = v2.w;
    }
    __syncthreads();  // also covers initial ht writes on the first chunk

#pragma unroll
    for (int kk = 0; kk < 16; ++kk) {
      const float4 wv1 = *(const float4*)&wt1[kk][fg * 4];
      const float4 wv2 = *(const float4*)&wt2[kk][fg * 4];
      const float4 ha = *(const float4*)&ht[kc * 16 + kk][ng * 4];
      const float hv[4] = {ha.x, ha.y, ha.z, ha.w};
#pragma unroll
      for (int i = 0; i < 4; ++i) {
        acc1[i][0] = fmaf(hv[i], wv1.x, acc1[i][0]);
        acc1[i][1] = fmaf(hv[i], wv1.y, acc1[i][1]);
        acc1[i][2] = fmaf(hv[i], wv1.z, acc1[i][2]);
        acc1[i][3] = fmaf(hv[i], wv1.w, acc1[i][3]);
        acc2[i][0] = fmaf(hv[i], wv2.x, acc2[i][0]);
        acc2[i][1] = fmaf(hv[i], wv2.y, acc2[i][1]);
        acc2[i][2] = fmaf(hv[i], wv2.z, acc2[i][2]);
        acc2[i][3] = fmaf(hv[i], wv2.w, acc2[i][3]);
      }
    }
    __syncthreads();
  }

#pragma unroll
  for (int i = 0; i < 4; ++i) {
    const long n = (long)blk * 32 + ng * 4 + i;
    float4 sv;
    sv.x = acc1[i][0] * acc2[i][0];
    sv.y = acc1[i][1] * acc2[i][1];
    sv.z = acc1[i][2] * acc2[i][2];
    sv.w = acc1[i][3] * acc2[i][3];
    *(float4*)(s_out + n * 128 + fg * 4) = sv;
  }
}

// ---------------------------------------------------------------------------
// Kernel B: out[o,n,f] = s[n,f] * sum_{a,b} (cg[o,a,b]+cg[o,b,a]) x[a,n,f] y[b,n,f]
// s lives in plane 0 of `out`; each thread reads its s before overwriting.
// launch_bounds(256,4): VGPR cap 128 so all 31 loads stay in one batch.
// ---------------------------------------------------------------------------
__global__ __launch_bounds__(256, 4) void tp_kernel(const float* __restrict__ x,
                                                    const float* __restrict__ y,
                                                    const float* __restrict__ cg,
                                                    float* out) {
  __shared__ float d[15 * 15 * 15];
  const int tid = threadIdx.x;
  for (int idx = tid; idx < 3375; idx += 256) {
    const int o = idx / 225;
    const int r = idx - o * 225;
    const int a = r / 15;
    const int b = r - a * 15;
    d[idx] = cg[idx] + cg[(o * 15 + b) * 15 + a];
  }
  __syncthreads();

  const long i = (long)blockIdx.x * 256 + tid;  // 0 .. 2,559,999
  const long off = 2 * i;                       // float2 offset within a plane

  float2 xv[15], yv[15];
#pragma unroll
  for (int a = 0; a < 15; ++a) xv[a] = *(const float2*)(x + a * NF + off);
#pragma unroll
  for (int b = 0; b < 15; ++b) yv[b] = *(const float2*)(y + b * NF + off);
  const float2 sv = *(const float2*)(out + off);  // s from plane 0 (own offset only)

#pragma unroll
  for (int o = 0; o < 15; ++o) {
    const int l3 = o / 5;
    const int m3 = o % 5 - 2;
    float2 acc = make_float2(0.f, 0.f);
    if (m3 >= -l3 && m3 <= l3) {
#pragma unroll
      for (int l1 = 0; l1 < 3; ++l1) {
#pragma unroll
        for (int l2 = 0; l2 < 3; ++l2) {
          const int ldiff = (l1 > l2) ? (l1 - l2) : (l2 - l1);
          if (l3 < ldiff || l3 > l1 + l2) continue;
          const int mlo = (-l1 > m3 - l2) ? -l1 : (m3 - l2);
          const int mhi = (l1 < m3 + l2) ? l1 : (m3 + l2);
#pragma unroll
          for (int m1 = mlo; m1 <= mhi; ++m1) {
            const int m2 = m3 - m1;
            const int a = l1 * 5 + m1 + 2;
            const int b = l2 * 5 + m2 + 2;
            const float dv = d[(o * 15 + a) * 15 + b];
            acc.x = fmaf(dv, xv[a].x * yv[b].x, acc.x);
            acc.y = fmaf(dv, xv[a].y * yv[b].y, acc.y);
          }
        }
      }
    }
    float2 res;
    res.x = acc.x * sv.x;
    res.y = acc.y * sv.y;
    // Non-temporal: out is never re-read; keep L3 space for x/y.
    __builtin_nontemporal_store(res.x, &out[o * NF + off]);
    __builtin_nontemporal_store(res.y, &out[o * NF + off + 1]);
  }
}

}  // namespace

extern "C" void kernel_launch(void* const* d_in, const int* in_sizes, int n_in,
                              void* d_out, int out_size, void* d_ws, size_t ws_size,
                              hipStream_t stream) {
  const float* x = (const float*)d_in[0];
  const float* y = (const float*)d_in[1];
  const float* g = (const float*)d_in[2];
  const float* w1 = (const float*)d_in[3];
  const float* w2 = (const float*)d_in[4];
  const float* cg = (const float*)d_in[5];
  float* out = (float*)d_out;

  // Pass 1: s[n,f] -> plane 0 of out (a guaranteed-zero output plane).
  s_kernel<<<1250, 256, 0, stream>>>(g, w1, w2, out);
  // Pass 2: streaming tensor-product contraction; overwrites all 15 planes.
  tp_kernel<<<10000, 256, 0, stream>>>(x, y, cg, out);
}

// Round 3
// 210.663 us; speedup vs baseline: 1.2491x; 1.0826x over previous
//
#include <hip/hip_runtime.h>
#include <array>

namespace {

constexpr int NPAIRS = 40000;
constexpr int F = 128;
constexpr long NF = (long)NPAIRS * F;  // 5,120,000 elements per (l,m) plane

// ---------------------------------------------------------------------------
// Compile-time enumeration of the nonzero CG terms:
// out[o] += (cg[o,a,b]+cg[o,b,a]) * x[a] * y[b]  over ordered pairs (a,b).
// ---------------------------------------------------------------------------
struct Term {
  int o, a, b;
};

constexpr int count_terms() {
  int idx = 0;
  for (int o = 0; o < 15; ++o) {
    const int l3 = o / 5, m3 = o % 5 - 2;
    if (m3 < -l3 || m3 > l3) continue;
    for (int l1 = 0; l1 < 3; ++l1)
      for (int l2 = 0; l2 < 3; ++l2) {
        const int ld = l1 > l2 ? l1 - l2 : l2 - l1;
        if (l3 < ld || l3 > l1 + l2) continue;
        const int mlo = (-l1 > m3 - l2) ? -l1 : m3 - l2;
        const int mhi = (l1 < m3 + l2) ? l1 : m3 + l2;
        for (int m1 = mlo; m1 <= mhi; ++m1) ++idx;
      }
  }
  return idx;
}
constexpr int NTERMS = count_terms();
static_assert(NTERMS == 117, "term count");

constexpr std::array<Term, NTERMS> make_terms() {
  std::array<Term, NTERMS> t{};
  int idx = 0;
  for (int o = 0; o < 15; ++o) {
    const int l3 = o / 5, m3 = o % 5 - 2;
    if (m3 < -l3 || m3 > l3) continue;
    for (int l1 = 0; l1 < 3; ++l1)
      for (int l2 = 0; l2 < 3; ++l2) {
        const int ld = l1 > l2 ? l1 - l2 : l2 - l1;
        if (l3 < ld || l3 > l1 + l2) continue;
        const int mlo = (-l1 > m3 - l2) ? -l1 : m3 - l2;
        const int mhi = (l1 < m3 + l2) ? l1 : m3 + l2;
        for (int m1 = mlo; m1 <= mhi; ++m1) {
          t[idx].o = o;
          t[idx].a = l1 * 5 + m1 + 2;
          t[idx].b = l2 * 5 + (m3 - m1) + 2;
          ++idx;
        }
      }
  }
  return t;
}
constexpr auto TERMS = make_terms();

// o -> dense accumulator index (only 9 of 15 output planes are nonzero).
constexpr std::array<int, 15> make_acc_idx() {
  std::array<int, 15> m{};
  for (int o = 0; o < 15; ++o) m[o] = -1;
  int q = 0;
  for (int o = 0; o < 15; ++o) {
    const int l3 = o / 5, m3 = o % 5 - 2;
    if (m3 >= -l3 && m3 <= l3) m[o] = q++;
  }
  return m;
}
constexpr auto ACC_IDX = make_acc_idx();

// ---------------------------------------------------------------------------
// Kernel A: s[n,f] = (sum_k w1[f,k] h[n,k]) * (sum_k w2[f,k] h[n,k])
// 32 n-rows per block, 1250 blocks, k-chunks of 16 (LDS ~33 KB).
// ---------------------------------------------------------------------------
__global__ __launch_bounds__(256, 4) void s_kernel(const float* __restrict__ g,
                                                   const float* __restrict__ w1,
                                                   const float* __restrict__ w2,
                                                   float* __restrict__ s_out) {
  __shared__ float ht[128][32];
  __shared__ float wt1[16][132];
  __shared__ float wt2[16][132];

  const int tid = threadIdx.x;
  const int blk = blockIdx.x;

  if (tid < 32) {
    const float gv = g[blk * 32 + tid];
    float hkm1 = 0.75112554446494248286f * expf(-0.5f * gv * gv);
    float hk = 1.41421356237309504880f * gv * hkm1;
    ht[0][tid] = hkm1;
    ht[1][tid] = hk;
#pragma unroll 1
    for (int k = 1; k <= 126; ++k) {
      const float kf = (float)k;
      const float hkp1 =
          sqrtf(2.0f / (kf + 1.0f)) * gv * hk - sqrtf(kf / (kf + 1.0f)) * hkm1;
      ht[k + 1][tid] = hkp1;
      hkm1 = hk;
      hk = hkp1;
    }
  }

  const int fg = tid & 31;
  const int ng = tid >> 5;

  float acc1[4][4];
  float acc2[4][4];
#pragma unroll
  for (int i = 0; i < 4; ++i)
#pragma unroll
    for (int j = 0; j < 4; ++j) {
      acc1[i][j] = 0.f;
      acc2[i][j] = 0.f;
    }

  for (int kc = 0; kc < 8; ++kc) {
#pragma unroll
    for (int it = 0; it < 2; ++it) {
      const int lin = tid + it * 256;
      const int f = lin >> 2;
      const int kq = lin & 3;
      const float4 v1 = *(const float4*)(w1 + f * 128 + kc * 16 + kq * 4);
      const float4 v2 = *(const float4*)(w2 + f * 128 + kc * 16 + kq * 4);
      wt1[kq * 4 + 0][f] = v1.x;
      wt1[kq * 4 + 1][f] = v1.y;
      wt1[kq * 4 + 2][f] = v1.z;
      wt1[kq * 4 + 3][f] = v1.w;
      wt2[kq * 4 + 0][f] = v2.x;
      wt2[kq * 4 + 1][f] = v2.y;
      wt2[kq * 4 + 2][f] = v2.z;
      wt2[kq * 4 + 3][f] = v2.w;
    }
    __syncthreads();

#pragma unroll
    for (int kk = 0; kk < 16; ++kk) {
      const float4 wv1 = *(const float4*)&wt1[kk][fg * 4];
      const float4 wv2 = *(const float4*)&wt2[kk][fg * 4];
      const float4 ha = *(const float4*)&ht[kc * 16 + kk][ng * 4];
      const float hv[4] = {ha.x, ha.y, ha.z, ha.w};
#pragma unroll
      for (int i = 0; i < 4; ++i) {
        acc1[i][0] = fmaf(hv[i], wv1.x, acc1[i][0]);
        acc1[i][1] = fmaf(hv[i], wv1.y, acc1[i][1]);
        acc1[i][2] = fmaf(hv[i], wv1.z, acc1[i][2]);
        acc1[i][3] = fmaf(hv[i], wv1.w, acc1[i][3]);
        acc2[i][0] = fmaf(hv[i], wv2.x, acc2[i][0]);
        acc2[i][1] = fmaf(hv[i], wv2.y, acc2[i][1]);
        acc2[i][2] = fmaf(hv[i], wv2.z, acc2[i][2]);
        acc2[i][3] = fmaf(hv[i], wv2.w, acc2[i][3]);
      }
    }
    __syncthreads();
  }

#pragma unroll
  for (int i = 0; i < 4; ++i) {
    const long n = (long)blk * 32 + ng * 4 + i;
    float4 sv;
    sv.x = acc1[i][0] * acc2[i][0];
    sv.y = acc1[i][1] * acc2[i][1];
    sv.z = acc1[i][2] * acc2[i][2];
    sv.w = acc1[i][3] * acc2[i][3];
    *(float4*)(s_out + n * 128 + fg * 4) = sv;
  }
}

// ---------------------------------------------------------------------------
// Kernel B: out[o,n,f] = s[n,f] * sum_t d2[t] x[a_t,n,f] y[b_t,n,f]
// s lives in plane 0 of `out` (a zero output plane); read before overwrite.
// amdgpu_waves_per_eu(4,4): pin occupancy at 16 waves/CU so the register
// allocator keeps all 30 global loads in one in-flight batch (~128 VGPR cap).
// ---------------------------------------------------------------------------
__global__ __attribute__((amdgpu_waves_per_eu(4, 4)))
__launch_bounds__(256) void tp_kernel(const float* __restrict__ x,
                                      const float* __restrict__ y,
                                      const float* __restrict__ cg,
                                      float* out) {
  __shared__ float d2[NTERMS];  // symmetrized coefficients, consumption order
  const int tid = threadIdx.x;
  if (tid < NTERMS) {
    const Term tm = TERMS[tid];
    d2[tid] = cg[(tm.o * 15 + tm.a) * 15 + tm.b] + cg[(tm.o * 15 + tm.b) * 15 + tm.a];
  }
  __syncthreads();

  const long i = (long)blockIdx.x * 256 + tid;  // 0 .. 2,559,999
  const long off = 2 * i;                       // float2 offset within a plane

  float2 xv[15], yv[15];
#pragma unroll
  for (int a = 0; a < 15; ++a) xv[a] = *(const float2*)(x + a * NF + off);
#pragma unroll
  for (int b = 0; b < 15; ++b) yv[b] = *(const float2*)(y + b * NF + off);
  const float2 sv = *(const float2*)(out + off);  // s from plane 0 (own offset)

  float accx[9], accy[9];
#pragma unroll
  for (int q = 0; q < 9; ++q) {
    accx[q] = 0.f;
    accy[q] = 0.f;
  }

#pragma unroll
  for (int t = 0; t < NTERMS; ++t) {
    const int o = TERMS[t].o;
    const int a = TERMS[t].a;
    const int b = TERMS[t].b;
    const int q = ACC_IDX[o];
    const float c = d2[t];
    accx[q] = fmaf(c, xv[a].x * yv[b].x, accx[q]);
    accy[q] = fmaf(c, xv[a].y * yv[b].y, accy[q]);
  }

#pragma unroll
  for (int o = 0; o < 15; ++o) {
    const int q = ACC_IDX[o];
    float2 r;
    if (q >= 0) {
      r.x = accx[q] * sv.x;
      r.y = accy[q] * sv.y;
    } else {
      r.x = 0.f;
      r.y = 0.f;
    }
    *(float2*)(out + o * NF + off) = r;
  }
}

}  // namespace

extern "C" void kernel_launch(void* const* d_in, const int* in_sizes, int n_in,
                              void* d_out, int out_size, void* d_ws, size_t ws_size,
                              hipStream_t stream) {
  const float* x = (const float*)d_in[0];
  const float* y = (const float*)d_in[1];
  const float* g = (const float*)d_in[2];
  const float* w1 = (const float*)d_in[3];
  const float* w2 = (const float*)d_in[4];
  const float* cg = (const float*)d_in[5];
  float* out = (float*)d_out;

  // Pass 1: s[n,f] -> plane 0 of out (a guaranteed-zero output plane).
  s_kernel<<<1250, 256, 0, stream>>>(g, w1, w2, out);
  // Pass 2: streaming tensor-product contraction; overwrites all 15 planes.
  tp_kernel<<<10000, 256, 0, stream>>>(x, y, cg, out);
}